// Round 10
// baseline (321.999 us; speedup 1.0000x reference)
//
#include <hip/hip_runtime.h>
#include <hip/hip_bf16.h>
#include <math.h>

#define N_NODES 10000
#define N_EDGES 640000
#define C 128
#define BF 16
#define EPB 32   // edges per k_msg block

typedef float    vfloat4 __attribute__((ext_vector_type(4)));
typedef float    vfloat2 __attribute__((ext_vector_type(2)));
typedef unsigned vuint2  __attribute__((ext_vector_type(2)));

__device__ __forceinline__ float2 bf2_to_f2(unsigned u) {
    union { unsigned x; float f; } lo, hi;
    lo.x = (u & 0xffffu) << 16;
    hi.x = u & 0xffff0000u;
    float2 r; r.x = lo.f; r.y = hi.f; return r;
}

// tanh-approx GELU, exp2 domain; |err vs exact| <= ~4e-4, branchless.
__device__ __forceinline__ float fast_gelu(float z) {
    float z2 = z * z;
    float p  = z * fmaf(0.044715f, z2, 1.0f);
    float e  = __builtin_amdgcn_exp2f(-2.3022082f * p);
    float r  = __builtin_amdgcn_rcpf(1.0f + e);
    return z * r;
}

__device__ __forceinline__ unsigned pack_bf16x2(float a, float b) {
    __hip_bfloat16 h0 = __float2bfloat16(a);
    __hip_bfloat16 h1 = __float2bfloat16(b);
    unsigned short u0, u1;
    __builtin_memcpy(&u0, &h0, 2);
    __builtin_memcpy(&u1, &h1, 2);
    return (unsigned)u0 | ((unsigned)u1 << 16);
}

// --- K1: fused x->bf16 convert (blocks 0..1249) + degree atomics (rest) ---
__global__ __launch_bounds__(256) void k_pre(
    const float* __restrict__ x, __hip_bfloat16* __restrict__ xb,
    const int* __restrict__ ei, int* __restrict__ dr, int* __restrict__ dc)
{
    int b = blockIdx.x;
    if (b < 1250) {
        int i = (b * 256 + threadIdx.x) * 4;
        float4 v = *(const float4*)(x + i);
        xb[i + 0] = __float2bfloat16(v.x);
        xb[i + 1] = __float2bfloat16(v.y);
        xb[i + 2] = __float2bfloat16(v.z);
        xb[i + 3] = __float2bfloat16(v.w);
    } else {
        int e = (b - 1250) * 256 + threadIdx.x;   // 2500 blocks cover N_EDGES
        atomicAdd(&dr[ei[e]], 1);
        atomicAdd(&dc[ei[N_EDGES + e]], 1);
    }
}

// --- K2: exclusive scan of dc -> off, plus inv-sqrt degrees ---
__global__ __launch_bounds__(1024) void k_scan(
    const int* __restrict__ dr, const int* __restrict__ dc,
    int* __restrict__ off, float* __restrict__ ir, float* __restrict__ ic)
{
    __shared__ int shp[1024];
    int t = threadIdx.x;
    int base = t * 10;
    int loc[10];
    int s = 0;
#pragma unroll
    for (int j = 0; j < 10; j++) {
        int i = base + j;
        int v = (i < N_NODES) ? dc[i] : 0;
        loc[j] = s;
        s += v;
    }
    shp[t] = s;
    __syncthreads();
    for (int st = 1; st < 1024; st <<= 1) {
        int a = (t >= st) ? shp[t - st] : 0;
        __syncthreads();
        shp[t] += a;
        __syncthreads();
    }
    int excl = shp[t] - s;
#pragma unroll
    for (int j = 0; j < 10; j++) {
        int i = base + j;
        if (i < N_NODES) {
            off[i] = excl + loc[j];
            ir[i] = rsqrtf((float)(dr[i] + 1));
            ic[i] = rsqrtf((float)(dc[i] + 1));
        }
    }
    if (t == 1023) off[N_NODES] = shp[1023];
}

// --- K3: edge-parallel messages. 256 thr = 4 waves x 64 channel-pairs;
//     ea staged in LDS (broadcast ds_read_b128), 2 channels/thread,
//     one full 256 B NT row-store per wave per edge. ---
__global__ __launch_bounds__(256) void k_msg(
    const int* __restrict__ ei, const float* __restrict__ ew,
    const float* __restrict__ ea,
    const __hip_bfloat16* __restrict__ xb,
    const float* __restrict__ Wb, const float* __restrict__ bb,
    const int* __restrict__ off, int* __restrict__ cur,
    const float* __restrict__ ir, const float* __restrict__ ic,
    __hip_bfloat16* __restrict__ msg)
{
    int e0 = blockIdx.x * EPB;                 // grid = N_EDGES/EPB exactly
    int t = threadIdx.x;
    int p = t & 63;                            // channel pair: channels 2p, 2p+1
    int w = t >> 6;                            // wave 0..3

    __shared__ __align__(16) float sl_ea[EPB][BF];
    __shared__ int   sl_slot[EPB];
    __shared__ float sl_s[EPB];
    __shared__ int   sl_r[EPB];

    // stage 32 edges x 16 feats (2 KB): coalesced NT 8 B/thread
    {
        vfloat2 v = __builtin_nontemporal_load(
            (const vfloat2*)(ea + (size_t)e0 * BF) + t);
        ((vfloat2*)&sl_ea[0][0])[t] = v;
    }
    if (t < EPB) {
        int e = e0 + t;
        int r = ei[e];
        int c = ei[N_EDGES + e];
        int pos = atomicAdd(&cur[c], 1);
        sl_slot[t] = off[c] + pos;
        sl_s[t] = ir[r] * ic[c] * ew[e];
        sl_r[t] = r;
    }

    // two W_bond columns per thread (L1-resident, hoisted over EPB edges)
    int c0 = p * 2;
    float wba[BF], wbb[BF];
#pragma unroll
    for (int k = 0; k < BF; k++) {
        float2 wf = *(const float2*)(Wb + (size_t)k * C + c0);
        wba[k] = wf.x; wbb[k] = wf.y;
    }
    float2 bbv = *(const float2*)(bb + c0);
    __syncthreads();

#pragma unroll 4
    for (int jj = 0; jj < EPB / 4; jj++) {
        int j = w + jj * 4;                    // this wave's edge
        const float4* er = (const float4*)sl_ea[j];   // wave-uniform -> broadcast
        float4 q0 = er[0], q1 = er[1], q2 = er[2], q3 = er[3];

        float e0f = bbv.x, e1f = bbv.y;
        e0f = fmaf(q0.x, wba[0], e0f);  e1f = fmaf(q0.x, wbb[0], e1f);
        e0f = fmaf(q0.y, wba[1], e0f);  e1f = fmaf(q0.y, wbb[1], e1f);
        e0f = fmaf(q0.z, wba[2], e0f);  e1f = fmaf(q0.z, wbb[2], e1f);
        e0f = fmaf(q0.w, wba[3], e0f);  e1f = fmaf(q0.w, wbb[3], e1f);
        e0f = fmaf(q1.x, wba[4], e0f);  e1f = fmaf(q1.x, wbb[4], e1f);
        e0f = fmaf(q1.y, wba[5], e0f);  e1f = fmaf(q1.y, wbb[5], e1f);
        e0f = fmaf(q1.z, wba[6], e0f);  e1f = fmaf(q1.z, wbb[6], e1f);
        e0f = fmaf(q1.w, wba[7], e0f);  e1f = fmaf(q1.w, wbb[7], e1f);
        e0f = fmaf(q2.x, wba[8], e0f);  e1f = fmaf(q2.x, wbb[8], e1f);
        e0f = fmaf(q2.y, wba[9], e0f);  e1f = fmaf(q2.y, wbb[9], e1f);
        e0f = fmaf(q2.z, wba[10], e0f); e1f = fmaf(q2.z, wbb[10], e1f);
        e0f = fmaf(q2.w, wba[11], e0f); e1f = fmaf(q2.w, wbb[11], e1f);
        e0f = fmaf(q3.x, wba[12], e0f); e1f = fmaf(q3.x, wbb[12], e1f);
        e0f = fmaf(q3.y, wba[13], e0f); e1f = fmaf(q3.y, wbb[13], e1f);
        e0f = fmaf(q3.z, wba[14], e0f); e1f = fmaf(q3.z, wbb[14], e1f);
        e0f = fmaf(q3.w, wba[15], e0f); e1f = fmaf(q3.w, wbb[15], e1f);

        int r = sl_r[j];
        float s = sl_s[j];
        int slot = sl_slot[j];
        float2 xf = bf2_to_f2(*((const unsigned*)(xb + (size_t)r * C) + p));
        float m0 = fast_gelu(xf.x + e0f) * s;
        float m1 = fast_gelu(xf.y + e1f) * s;
        __builtin_nontemporal_store(pack_bf16x2(m0, m1),
            (unsigned*)(msg + (size_t)slot * C) + p);   // 64 lanes = full row
    }
}

// --- K4: per-node sum of bf16 msg rows (8 row-groups x 32 channel-quads,
//     NT uint2 loads) + self-loop + split GEMV epilogue. ---
__global__ __launch_bounds__(256) void k_sum(
    const __hip_bfloat16* __restrict__ msg,
    const __hip_bfloat16* __restrict__ xb,
    const float* __restrict__ ir, const float* __restrict__ ic,
    const int* __restrict__ off,
    const float* __restrict__ Wl, const float* __restrict__ bl,
    float* __restrict__ out)
{
    int n = blockIdx.x;
    int t = threadIdx.x;
    int q = t & 31;           // channel quad: channels 4q..4q+3
    int g = t >> 5;           // row group 0..7

    int o0 = off[n];
    int cnt = off[n + 1] - o0;
    const vuint2* base = (const vuint2*)(msg + (size_t)o0 * C) + q;  // stride 32/row

    float a0 = 0.f, a1 = 0.f, a2 = 0.f, a3 = 0.f;
    float b0 = 0.f, b1 = 0.f, b2 = 0.f, b3 = 0.f;
    int i = g;
    for (; i + 8 < cnt; i += 16) {
        vuint2 u = __builtin_nontemporal_load(base + (size_t)i * 32);
        vuint2 v = __builtin_nontemporal_load(base + (size_t)(i + 8) * 32);
        float2 f0 = bf2_to_f2(u.x), f1 = bf2_to_f2(u.y);
        float2 g0 = bf2_to_f2(v.x), g1 = bf2_to_f2(v.y);
        a0 += f0.x; a1 += f0.y; a2 += f1.x; a3 += f1.y;
        b0 += g0.x; b1 += g0.y; b2 += g1.x; b3 += g1.y;
    }
    if (i < cnt) {
        vuint2 u = __builtin_nontemporal_load(base + (size_t)i * 32);
        float2 f0 = bf2_to_f2(u.x), f1 = bf2_to_f2(u.y);
        a0 += f0.x; a1 += f0.y; a2 += f1.x; a3 += f1.y;
    }
    a0 += b0; a1 += b1; a2 += b2; a3 += b3;

    __shared__ float4 shp[8][32];
    __shared__ float  shs[C];
    __shared__ float  sho[2][C];
    shp[g][q] = make_float4(a0, a1, a2, a3);
    __syncthreads();
    if (t < 32) {
        float4 s = shp[0][t];
#pragma unroll
        for (int k = 1; k < 8; k++) {
            float4 v = shp[k][t];
            s.x += v.x; s.y += v.y; s.z += v.z; s.w += v.w;
        }
        float sl = ir[n] * ic[n];
        uint2 xu = *((const uint2*)(xb + (size_t)n * C) + t);
        float2 x0 = bf2_to_f2(xu.x), x1 = bf2_to_f2(xu.y);
        shs[4 * t + 0] = s.x + fast_gelu(x0.x) * sl;
        shs[4 * t + 1] = s.y + fast_gelu(x0.y) * sl;
        shs[4 * t + 2] = s.z + fast_gelu(x1.x) * sl;
        shs[4 * t + 3] = s.w + fast_gelu(x1.y) * sl;
    }
    __syncthreads();

    int ch = t & 127, half = t >> 7;
    float o = 0.f;
    const float4* shv = (const float4*)shs + half * 16;
    const float* wcol = Wl + (size_t)(half * 64) * C + ch;
#pragma unroll 8
    for (int k4 = 0; k4 < 16; k4++) {
        float4 sv = shv[k4];
        o = fmaf(sv.x, wcol[(size_t)(k4 * 4 + 0) * C], o);
        o = fmaf(sv.y, wcol[(size_t)(k4 * 4 + 1) * C], o);
        o = fmaf(sv.z, wcol[(size_t)(k4 * 4 + 2) * C], o);
        o = fmaf(sv.w, wcol[(size_t)(k4 * 4 + 3) * C], o);
    }
    sho[half][ch] = o;
    __syncthreads();
    if (t < C) out[(size_t)n * C + t] = bl[t] + sho[0][t] + sho[1][t];
}

// ---------------- fallback path (round-5 structure, ws-lean) ----------------
__global__ void k_deg_fb(const int* __restrict__ ei, int* __restrict__ dr, int* __restrict__ dc) {
    int e = blockIdx.x * blockDim.x + threadIdx.x;
    if (e < N_EDGES) {
        atomicAdd(&dr[ei[e]], 1);
        atomicAdd(&dc[ei[N_EDGES + e]], 1);
    }
}

__global__ __launch_bounds__(256) void k_cvt_fb(const float* __restrict__ x,
                                                __hip_bfloat16* __restrict__ xb) {
    int i = (blockIdx.x * 256 + threadIdx.x) * 4;
    float4 v = *(const float4*)(x + i);
    xb[i + 0] = __float2bfloat16(v.x);
    xb[i + 1] = __float2bfloat16(v.y);
    xb[i + 2] = __float2bfloat16(v.z);
    xb[i + 3] = __float2bfloat16(v.w);
}

__global__ void k_scatter(const int* __restrict__ ei, const int* __restrict__ off,
                          int* __restrict__ cur, int* __restrict__ bucket) {
    int e = blockIdx.x * blockDim.x + threadIdx.x;
    if (e < N_EDGES) {
        int c = ei[N_EDGES + e];
        int pos = atomicAdd(&cur[c], 1);
        bucket[off[c] + pos] = e;
    }
}

template <bool USEBF>
__global__ __launch_bounds__(512) void k_node_fb(
    const float* __restrict__ x, const __hip_bfloat16* __restrict__ xb,
    const float* __restrict__ ea, const float* __restrict__ ew,
    const float* __restrict__ Wb, const float* __restrict__ bb,
    const int* __restrict__ ei,
    const float* __restrict__ ir, const float* __restrict__ ic,
    const int* __restrict__ off, const int* __restrict__ bucket,
    const float* __restrict__ Wl, const float* __restrict__ bl,
    float* __restrict__ out)
{
    int n = blockIdx.x;
    int t = threadIdx.x & (C - 1);
    int g = threadIdx.x >> 7;
    float icn = ic[n];
    float wb[BF];
#pragma unroll
    for (int k = 0; k < BF; k++) wb[k] = Wb[(size_t)k * C + t];
    float bbt = bb[t];
    float acc = 0.0f;
    if (g == 0) {
        float xv = USEBF ? __bfloat162float(xb[(size_t)n * C + t]) : x[(size_t)n * C + t];
        acc = fast_gelu(xv) * (ir[n] * icn);
    }
    int o0 = off[n], o1 = off[n + 1];
    for (int i = o0 + g; i < o1; i += 4) {
        int e = __builtin_amdgcn_readfirstlane(bucket[i]);
        int r = ei[e];
        float s = ir[r] * icn * ew[e];
        const float4* eapt = (const float4*)(ea + (size_t)e * BF);
        float4 q0 = eapt[0], q1 = eapt[1], q2 = eapt[2], q3 = eapt[3];
        float emb = bbt;
        emb = fmaf(q0.x, wb[0], emb);  emb = fmaf(q0.y, wb[1], emb);
        emb = fmaf(q0.z, wb[2], emb);  emb = fmaf(q0.w, wb[3], emb);
        emb = fmaf(q1.x, wb[4], emb);  emb = fmaf(q1.y, wb[5], emb);
        emb = fmaf(q1.z, wb[6], emb);  emb = fmaf(q1.w, wb[7], emb);
        emb = fmaf(q2.x, wb[8], emb);  emb = fmaf(q2.y, wb[9], emb);
        emb = fmaf(q2.z, wb[10], emb); emb = fmaf(q2.w, wb[11], emb);
        emb = fmaf(q3.x, wb[12], emb); emb = fmaf(q3.y, wb[13], emb);
        emb = fmaf(q3.z, wb[14], emb); emb = fmaf(q3.w, wb[15], emb);
        float xv = USEBF ? __bfloat162float(xb[(size_t)r * C + t]) : x[(size_t)r * C + t];
        acc = fmaf(fast_gelu(xv + emb), s, acc);
    }
    __shared__ float shp[4][C];
    __shared__ float shs[C];
    shp[g][t] = acc;
    __syncthreads();
    if (threadIdx.x < C) {
        int k = threadIdx.x;
        shs[k] = shp[0][k] + shp[1][k] + shp[2][k] + shp[3][k];
    }
    __syncthreads();
    float o = 0.0f;
    int k0 = g * 32;
#pragma unroll 8
    for (int j = 0; j < 32; j++) {
        int k = k0 + j;
        o = fmaf(shs[k], Wl[(size_t)k * C + t], o);
    }
    shp[g][t] = o;
    __syncthreads();
    if (threadIdx.x < C) {
        int c = threadIdx.x;
        out[(size_t)n * C + c] = bl[c] + shp[0][c] + shp[1][c] + shp[2][c] + shp[3][c];
    }
}

extern "C" void kernel_launch(void* const* d_in, const int* in_sizes, int n_in,
                              void* d_out, int out_size, void* d_ws, size_t ws_size,
                              hipStream_t stream) {
    const float* x  = (const float*)d_in[0];
    const float* ea = (const float*)d_in[1];
    const float* ew = (const float*)d_in[2];
    const float* Wb = (const float*)d_in[3];
    const float* bb = (const float*)d_in[4];
    const float* Wl = (const float*)d_in[5];
    const float* bl = (const float*)d_in[6];
    const int*   ei = (const int*)d_in[7];
    float* out = (float*)d_out;

    const size_t msg_elems = (size_t)N_EDGES * C;                 // 81,920,000
    const size_t need_full = msg_elems * 2 + 1280000ull * 2 + (10304 + 5 * 10240) * 4;
    const size_t need_bf   = (size_t)(640000 + 640000 + 10304 + 5 * 10240) * 4;

    if (ws_size >= need_full) {
        __hip_bfloat16* msg = (__hip_bfloat16*)d_ws;
        __hip_bfloat16* xb  = msg + msg_elems;
        int*   off = (int*)(xb + 1280000);
        int*   dr  = off + 10304;
        int*   dc  = dr + 10240;
        int*   cur = dc + 10240;
        float* ir  = (float*)(cur + 10240);
        float* ic  = ir + 10240;

        hipMemsetAsync(dr, 0, 3 * 10240 * sizeof(int), stream);   // dr, dc, cur
        k_pre<<<3750, 256, 0, stream>>>(x, xb, ei, dr, dc);
        k_scan<<<1, 1024, 0, stream>>>(dr, dc, off, ir, ic);
        k_msg<<<N_EDGES / EPB, 256, 0, stream>>>(ei, ew, ea, xb, Wb, bb, off, cur, ir, ic, msg);
        k_sum<<<N_NODES, 256, 0, stream>>>(msg, xb, ir, ic, off, Wl, bl, out);
    } else {
        bool usebf = ws_size >= need_bf;
        unsigned* w32 = (unsigned*)d_ws;
        __hip_bfloat16* xb = (__hip_bfloat16*)w32;
        int* bucket = (int*)(w32 + (usebf ? 640000 : 0));
        int* off    = bucket + 640000;
        int* dr     = off + 10304;
        int* dc     = dr + 10240;
        int* cur    = dc + 10240;
        float* ir   = (float*)(cur + 10240);
        float* ic   = ir + 10240;

        hipMemsetAsync(dr, 0, 3 * 10240 * sizeof(int), stream);
        if (usebf) k_cvt_fb<<<1250, 256, 0, stream>>>(x, xb);
        k_deg_fb<<<(N_EDGES + 255) / 256, 256, 0, stream>>>(ei, dr, dc);
        k_scan<<<1, 1024, 0, stream>>>(dr, dc, off, ir, ic);
        k_scatter<<<(N_EDGES + 255) / 256, 256, 0, stream>>>(ei, off, cur, bucket);
        if (usebf)
            k_node_fb<true><<<N_NODES, 512, 0, stream>>>(x, xb, ea, ew, Wb, bb, ei, ir, ic, off, bucket, Wl, bl, out);
        else
            k_node_fb<false><<<N_NODES, 512, 0, stream>>>(x, xb, ea, ew, Wb, bb, ei, ir, ic, off, bucket, Wl, bl, out);
    }
}